// Round 1
// 10008.582 us; speedup vs baseline: 1.0238x; 1.0238x over previous
//
#include <hip/hip_runtime.h>
#include <cstddef>
#include <cstdint>

#define T_STEPS 256
#define BATCH   512
#define NIN     128
#define NHID    1024
#define NWGS    256

typedef _Float16 half8  __attribute__((ext_vector_type(8)));
typedef float    float4v __attribute__((ext_vector_type(4)));
typedef float    float2v __attribute__((ext_vector_type(2)));

__device__ __forceinline__ float sigmoid_f(float x) { return 1.0f / (1.0f + __expf(-x)); }
__device__ __forceinline__ float tanh_f(float x) {
    float ax = fabsf(x);
    float t  = __expf(-2.0f * ax);
    float r  = (1.0f - t) / (1.0f + t);
    return copysignf(r, x);
}

// LDS map (dynamic, ~152 KB)
// zw stride 36 floats: epilogue writes 2-way (free), float2 gate reads 4-way-balanced
// (minimum for b64) instead of the old 16-way scalar reads.
#define WLDS_OFF  0         // 131072 B: weight B-frags [nt 2][kt 64][lane 64][16B]
#define WHF_OFF   131072    // 4096 B:  proj B-frags [kt 4][lane 64][16B]
#define ZS_OFF    135168    // 18432 B: per-wave z scratch (2304 B each, 16 rows x 36 f32)
#define ZW_BYTES  2304
#define HS_OFF    153600    // 2048 B:  per-wave h scratch (256 B each)
#define BIASG_OFF 155648    // 128 B:   gate bias [g 4][u 8] f32
#define BH_OFF    155776    // 32 B:    proj bias [u 8] f32
#define SMEM_BYTES 155808

// ---------------------------------------------------------------------------
// Grid barrier (agent scope).
// ---------------------------------------------------------------------------
__device__ __forceinline__ void grid_barrier(uint32_t* cnt, uint32_t* gen,
                                             uint32_t target_gen) {
    __syncthreads();
    if (threadIdx.x == 0) {
        __threadfence();
        uint32_t old = __hip_atomic_fetch_add(cnt, 1u, __ATOMIC_RELAXED,
                                              __HIP_MEMORY_SCOPE_AGENT);
        if (old == target_gen * NWGS - 1)
            __hip_atomic_store(gen, target_gen, __ATOMIC_RELAXED,
                               __HIP_MEMORY_SCOPE_AGENT);
        uint32_t spins = 0;
        while (__hip_atomic_load(gen, __ATOMIC_RELAXED,
                                 __HIP_MEMORY_SCOPE_AGENT) < target_gen) {
            __builtin_amdgcn_s_sleep(8);
            if (++spins > 20000000u) break;
        }
        __threadfence();
    }
    __syncthreads();
}

// ---------------------------------------------------------------------------
// One-time x -> fp16 A-frag conversion.
// xf[t 256][mt 32][kt 4][512 halves]; value = x[mt*16+(lane&15)][t][kt*32+(lane>>4)*8+j]
// Grid (32 mt, 16 tb), 256 thr.
// ---------------------------------------------------------------------------
__global__ __launch_bounds__(256)
void xconv_kernel(const float* __restrict__ x, _Float16* __restrict__ xf)
{
    __shared__ float xs[16][2][128];
    const int mt = blockIdx.x, tb = blockIdx.y;
    const int t = threadIdx.x;
    for (int tl = 0; tl < 8; ++tl) {
        __syncthreads();
#pragma unroll
        for (int i = 0; i < 4; ++i) {
            const int idx = t + i * 256;
            const int m = idx >> 6, rest = idx & 63;
            const int t2 = rest >> 5, k4 = rest & 31;
            float4v v = *(const float4v*)(x +
                ((size_t)(mt * 16 + m) * T_STEPS + (tb * 16 + tl * 2 + t2)) * NIN + k4 * 4);
            *(float4v*)&xs[m][t2][k4 * 4] = v;
        }
        __syncthreads();
#pragma unroll
        for (int i = 0; i < 2; ++i) {
            const int idx = t + i * 256;
            const int t2 = idx >> 8, rest = idx & 255;
            const int kt = rest >> 6, lane = rest & 63;
            half8 hv;
#pragma unroll
            for (int j = 0; j < 8; ++j)
                hv[j] = (_Float16)xs[lane & 15][t2][kt * 32 + (lane >> 4) * 8 + j];
            const int tg = tb * 16 + tl * 2 + t2;
            *(half8*)(xf + (((size_t)tg * 32 + mt) * 4 + kt) * 512 + lane * 8) = hv;
        }
    }
}

// ---------------------------------------------------------------------------
// Persistent kernel.  256 WGs x 512 thr, 1 WG/CU (152 KB LDS).
// WG: layer = bid&1, slice s = bid>>1 (8 units).  Weights fp16 LDS-pinned.
// GEMM: M=512 (8 waves x 4 mt), N=32 (2 nt), K=2048 (64 kt).
// Depth-4 A-frag register pipeline hides L2/LLC latency.
// proj runs on layer-1 WGs (load balance: l0 = gemm, l1 = gemm + proj).
// ---------------------------------------------------------------------------
__global__ __launch_bounds__(512, 2)
void persist_kernel(const float* __restrict__ k1, const float* __restrict__ b1,
                    const float* __restrict__ k2, const float* __restrict__ b2,
                    const float* __restrict__ W_h, const float* __restrict__ b_h,
                    const _Float16* __restrict__ xf,
                    uint8_t* wsb, float* __restrict__ out,
                    uint32_t* barrier_mem)
{
    extern __shared__ __align__(16) char smem[];
    const size_t MB = 1024 * 1024;
    _Float16* A1b[2] = {(_Float16*)(wsb + 0 * MB), (_Float16*)(wsb + 2 * MB)};
    _Float16* A2b[2] = {(_Float16*)(wsb + 4 * MB), (_Float16*)(wsb + 6 * MB)};
    uint32_t* cnt = barrier_mem;
    uint32_t* gen = barrier_mem + 32;

    const int tid = threadIdx.x;
    const int w = tid >> 6, lane = tid & 63;
    const int q = lane >> 4, n16 = lane & 15;
    const int bid = blockIdx.x;
    const int layer = bid & 1;
    const int s = bid >> 1;          // 0..127
    const int u0 = s * 8;

    const float* ksrc = layer ? k2 : k1;
    const float* bsrc = layer ? b2 : b1;

    // ---- init: convert weight slice f32 -> fp16 frags in LDS ----
    {
#pragma unroll 1
        for (int i = 0; i < 16; ++i) {
            const int kt = w * 8 + (i & 7);
            const int nt = i >> 3;
            const int colg = (nt * 2 + (n16 >> 3)) * 1024 + u0 + (n16 & 7);
            half8 hv;
#pragma unroll
            for (int j = 0; j < 8; ++j)
                hv[j] = (_Float16)ksrc[(size_t)(kt * 32 + q * 8 + j) * 4096 + colg];
            *(half8*)(smem + WLDS_OFF + (nt * 64 + kt) * 1024 + lane * 16) = hv;
        }
    }
    if (tid < 32)
        ((float*)(smem + BIASG_OFF))[tid] = bsrc[(tid >> 3) * 1024 + u0 + (tid & 7)];
    if (layer == 1) {   // proj lives on layer-1 WGs now
        if (tid < 256) {
            const int kt = tid >> 6, ln = tid & 63;
            const int nn = ln & 15;
            half8 hv;
#pragma unroll
            for (int j = 0; j < 8; ++j) {
                float v = (nn < 8)
                    ? W_h[(size_t)(kt * 32 + (ln >> 4) * 8 + j) * NHID + u0 + nn] : 0.f;
                hv[j] = (_Float16)v;
            }
            *(half8*)(smem + WHF_OFF + kt * 1024 + ln * 16) = hv;
        }
        if (tid < 8) ((float*)(smem + BH_OFF))[tid] = b_h[u0 + tid];
    }
    __syncthreads();

    const float* bg = (const float*)(smem + BIASG_OFF);
    const float* bh = (const float*)(smem + BH_OFF);
    float* zw = (float*)(smem + ZS_OFF + w * ZW_BYTES);     // [16 rows][36 f32]
    _Float16* hw = (_Float16*)(smem + HS_OFF + w * 256);    // [16 rows][8 u]

    // c state: lane owns (row = n16, units q*2, q*2+1) per mt
    float cst[4][2];
#pragma unroll
    for (int mt = 0; mt < 4; ++mt) { cst[mt][0] = 0.f; cst[mt][1] = 0.f; }

    // ---- proj body (layer-1 WGs): pf(t) -> A1dst low half ----
    auto proj_step = [&](int tstep, _Float16* A1dst) {
        float4v pacc[4];
#pragma unroll
        for (int mt = 0; mt < 4; ++mt) pacc[mt] = (float4v){0.f, 0.f, 0.f, 0.f};
        half8 Bp[4];
        half8 Ap[4][4];
#pragma unroll
        for (int kt = 0; kt < 4; ++kt) {
            Bp[kt] = *(const half8*)(smem + WHF_OFF + kt * 1024 + lane * 16);
#pragma unroll
            for (int mt = 0; mt < 4; ++mt)
                Ap[kt][mt] = *(const half8*)(xf +
                    (((size_t)tstep * 32 + (w * 4 + mt)) * 4 + kt) * 512 + lane * 8);
        }
#pragma unroll
        for (int kt = 0; kt < 4; ++kt)
#pragma unroll
            for (int mt = 0; mt < 4; ++mt)
                pacc[mt] = __builtin_amdgcn_mfma_f32_16x16x32_f16(Ap[kt][mt], Bp[kt], pacc[mt], 0, 0, 0);
#pragma unroll 1
        for (int mt = 0; mt < 4; ++mt) {
            if (n16 < 8) {
#pragma unroll
                for (int r = 0; r < 4; ++r)
                    zw[(q * 4 + r) * 9 + n16] = pacc[mt][r];   // stride 9: conflict-free
            }
            if (lane < 16) {        // wave-internal LDS: DS ops in-order per wave
                half8 hv;
#pragma unroll
                for (int u = 0; u < 8; ++u)
                    hv[u] = (_Float16)fmaxf(zw[lane * 9 + u] + bh[u], 0.f);
                const int mtg = w * 4 + mt;
                *(half8*)(A1dst + ((size_t)mtg * 64 + (s >> 2)) * 512
                                + ((s & 3) * 16 + lane) * 8) = hv;
            }
        }
    };

    // ---- LSTM GEMM + fused epilogue, depth-4 A prefetch + B double-buffer ----
    auto gemm_step = [&](const _Float16* Asrc, _Float16* hdst1, _Float16* hdst2,
                         float* outp) {
        float4v acc[4][2];
#pragma unroll
        for (int mt = 0; mt < 4; ++mt) {
            acc[mt][0] = (float4v){0.f, 0.f, 0.f, 0.f};
            acc[mt][1] = (float4v){0.f, 0.f, 0.f, 0.f};
        }
        const char* aw[4];
#pragma unroll
        for (int mt = 0; mt < 4; ++mt)
            aw[mt] = (const char*)Asrc + ((size_t)(w * 4 + mt) * 64) * 1024 + lane * 16;

        half8 Ab[4][4];
#pragma unroll
        for (int d = 0; d < 3; ++d)
#pragma unroll
            for (int mt = 0; mt < 4; ++mt)
                Ab[d][mt] = *(const half8*)(aw[mt] + (size_t)d * 1024);
        half8 Bb[2][2];
        Bb[0][0] = *(const half8*)(smem + WLDS_OFF + lane * 16);
        Bb[0][1] = *(const half8*)(smem + WLDS_OFF + 65536 + lane * 16);

#pragma unroll 4
        for (int kt = 0; kt < 60; ++kt) {
            const int cur = kt & 3, nxt = (kt + 3) & 3, bc = kt & 1;
#pragma unroll
            for (int mt = 0; mt < 4; ++mt)
                Ab[nxt][mt] = *(const half8*)(aw[mt] + (size_t)(kt + 3) * 1024);
            Bb[bc ^ 1][0] = *(const half8*)(smem + WLDS_OFF + (kt + 1) * 1024 + lane * 16);
            Bb[bc ^ 1][1] = *(const half8*)(smem + WLDS_OFF + 65536 + (kt + 1) * 1024 + lane * 16);
#pragma unroll
            for (int mt = 0; mt < 4; ++mt)
                acc[mt][0] = __builtin_amdgcn_mfma_f32_16x16x32_f16(Ab[cur][mt], Bb[bc][0], acc[mt][0], 0, 0, 0);
#pragma unroll
            for (int mt = 0; mt < 4; ++mt)
                acc[mt][1] = __builtin_amdgcn_mfma_f32_16x16x32_f16(Ab[cur][mt], Bb[bc][1], acc[mt][1], 0, 0, 0);
        }
#pragma unroll
        for (int kt = 60; kt < 64; ++kt) {
            const int cur = kt & 3, bc = kt & 1;
            if (kt == 60) {
#pragma unroll
                for (int mt = 0; mt < 4; ++mt)
                    Ab[3][mt] = *(const half8*)(aw[mt] + (size_t)63 * 1024);
            }
            if (kt < 63) {
                Bb[bc ^ 1][0] = *(const half8*)(smem + WLDS_OFF + (kt + 1) * 1024 + lane * 16);
                Bb[bc ^ 1][1] = *(const half8*)(smem + WLDS_OFF + 65536 + (kt + 1) * 1024 + lane * 16);
            }
#pragma unroll
            for (int mt = 0; mt < 4; ++mt)
                acc[mt][0] = __builtin_amdgcn_mfma_f32_16x16x32_f16(Ab[cur][mt], Bb[bc][0], acc[mt][0], 0, 0, 0);
#pragma unroll
            for (int mt = 0; mt < 4; ++mt)
                acc[mt][1] = __builtin_amdgcn_mfma_f32_16x16x32_f16(Ab[cur][mt], Bb[bc][1], acc[mt][1], 0, 0, 0);
        }

        // epilogue per mt (cols: g*8+u), zw stride 36
#pragma unroll 1
        for (int mt = 0; mt < 4; ++mt) {
#pragma unroll
            for (int nt = 0; nt < 2; ++nt)
#pragma unroll
                for (int r = 0; r < 4; ++r)
                    zw[(q * 4 + r) * 36 + nt * 16 + n16] = acc[mt][nt][r];
            const float* zr = zw + n16 * 36 + q * 2;
            float2v vi = *(const float2v*)(zr + 0);
            float2v vj = *(const float2v*)(zr + 8);
            float2v vf = *(const float2v*)(zr + 16);
            float2v vo = *(const float2v*)(zr + 24);
            float hvals[2];
#pragma unroll
            for (int uu = 0; uu < 2; ++uu) {
                const int u = q * 2 + uu;
                const float zi = vi[uu] + bg[u];
                const float zj = vj[uu] + bg[8 + u];
                const float zf = vf[uu] + bg[16 + u];
                const float zo = vo[uu] + bg[24 + u];
                float c = cst[mt][uu] * sigmoid_f(zf + 1.0f) + sigmoid_f(zi) * tanh_f(zj);
                cst[mt][uu] = c;
                hvals[uu] = tanh_f(c) * sigmoid_f(zo);
            }
            hw[n16 * 8 + q * 2 + 0] = (_Float16)hvals[0];
            hw[n16 * 8 + q * 2 + 1] = (_Float16)hvals[1];
            if (outp) {
                const int row = (w * 4 + mt) * 16 + n16;
                outp[(size_t)row * NHID + u0 + q * 2 + 0] = hvals[0];
                outp[(size_t)row * NHID + u0 + q * 2 + 1] = hvals[1];
            }
            if (lane < 16) {
                half8 hv = *(half8*)(hw + lane * 8);
                const size_t loff = ((s & 3) * 16 + lane) * 8;
                const int mtg = w * 4 + mt;
                *(half8*)(hdst1 + ((size_t)mtg * 64 + 32 + (s >> 2)) * 512 + loff) = hv;
                if (hdst2)
                    *(half8*)(hdst2 + ((size_t)mtg * 64 + (s >> 2)) * 512 + loff) = hv;
            }
        }
    };

    // ---- pre-phase: proj(0) -> A1[0].low (layer-1 WGs) ----
    if (layer == 1) proj_step(0, A1b[0]);
    grid_barrier(cnt, gen, 1u);

    // ---- phases ----
    for (int p = 0; p <= 256; ++p) {
        const int pi = p & 1, po = pi ^ 1;
        if (layer == 0) {
            if (p <= 255)
                gemm_step(A1b[pi], A1b[po], A2b[po], nullptr);   // h1 -> A1hi, A2lo
        } else {
            if (p >= 1)
                gemm_step(A2b[pi], A2b[po], nullptr,
                          (p == 256) ? out : nullptr);           // h2 -> A2hi
            if (p + 1 <= 255)
                proj_step(p + 1, A1b[po]);                       // pf(t+1) -> A1lo
        }
        grid_barrier(cnt, gen, (uint32_t)(p + 2));
    }
}

// ---------------------------------------------------------------------------
extern "C" void kernel_launch(void* const* d_in, const int* in_sizes, int n_in,
                              void* d_out, int out_size, void* d_ws, size_t ws_size,
                              hipStream_t stream)
{
    const float* x   = (const float*)d_in[0];
    const float* W_h = (const float*)d_in[1];
    const float* b_h = (const float*)d_in[2];
    const float* k1  = (const float*)d_in[3];
    const float* b1  = (const float*)d_in[4];
    const float* k2  = (const float*)d_in[5];
    const float* b2  = (const float*)d_in[6];
    float* out = (float*)d_out;

    const size_t MB = 1024 * 1024;
    uint8_t* wsb = (uint8_t*)d_ws;
    // A1[0] 0-2, A1[1] 2-4, A2[0] 4-6, A2[1] 6-8 MB ; xf 8-40 MB ; barrier @40 MB
    _Float16* xf = (_Float16*)(wsb + 8 * MB);
    uint32_t* barrier_mem = (uint32_t*)(wsb + 40 * MB);

    hipFuncSetAttribute((const void*)persist_kernel,
                        hipFuncAttributeMaxDynamicSharedMemorySize, SMEM_BYTES);

    hipMemsetAsync(wsb, 0, 8 * MB, stream);          // zero all A-buffers
    hipMemsetAsync(barrier_mem, 0, 4096, stream);
    xconv_kernel<<<dim3(32, 16), 256, 0, stream>>>(x, xf);
    persist_kernel<<<NWGS, 512, SMEM_BYTES, stream>>>(
        k1, b1, k2, b2, W_h, b_h, xf, wsb, out, barrier_mem);
}

// Round 2
// 9847.427 us; speedup vs baseline: 1.0405x; 1.0164x over previous
//
#include <hip/hip_runtime.h>
#include <cstddef>
#include <cstdint>

#define T_STEPS 256
#define BATCH   512
#define NIN     128
#define NHID    1024
#define NWGS    256

typedef _Float16 half8  __attribute__((ext_vector_type(8)));
typedef float    float4v __attribute__((ext_vector_type(4)));
typedef float    float2v __attribute__((ext_vector_type(2)));

__device__ __forceinline__ float sigmoid_f(float x) { return 1.0f / (1.0f + __expf(-x)); }
__device__ __forceinline__ float tanh_f(float x) {
    float ax = fabsf(x);
    float t  = __expf(-2.0f * ax);
    float r  = (1.0f - t) / (1.0f + t);
    return copysignf(r, x);
}

// LDS map (dynamic, ~152 KB)
#define WLDS_OFF  0         // 131072 B: weight B-frags [nt 2][kt 64][lane 64][16B]
#define WHF_OFF   131072    // 4096 B:  proj B-frags [kt 4][lane 64][16B]
#define ZS_OFF    135168    // 18432 B: per-wave z scratch (2304 B each, 16 rows x 36 f32)
#define ZW_BYTES  2304
#define HS_OFF    153600    // 2048 B:  per-wave h scratch (256 B each)
#define BIASG_OFF 155648    // 128 B:   gate bias [g 4][u 8] f32
#define BH_OFF    155776    // 32 B:    proj bias [u 8] f32
#define SMEM_BYTES 155808

// ---------------------------------------------------------------------------
// Grid barrier (agent scope).
// ---------------------------------------------------------------------------
__device__ __forceinline__ void grid_barrier(uint32_t* cnt, uint32_t* gen,
                                             uint32_t target_gen) {
    __syncthreads();
    if (threadIdx.x == 0) {
        __threadfence();
        uint32_t old = __hip_atomic_fetch_add(cnt, 1u, __ATOMIC_RELAXED,
                                              __HIP_MEMORY_SCOPE_AGENT);
        if (old == target_gen * NWGS - 1)
            __hip_atomic_store(gen, target_gen, __ATOMIC_RELAXED,
                               __HIP_MEMORY_SCOPE_AGENT);
        uint32_t spins = 0;
        while (__hip_atomic_load(gen, __ATOMIC_RELAXED,
                                 __HIP_MEMORY_SCOPE_AGENT) < target_gen) {
            __builtin_amdgcn_s_sleep(8);
            if (++spins > 20000000u) break;
        }
        __threadfence();
    }
    __syncthreads();
}

// ---------------------------------------------------------------------------
// One-time x -> fp16 A-frag conversion.
// xf[t 256][mt 32][kt 4][512 halves]; value = x[mt*16+(lane&15)][t][kt*32+(lane>>4)*8+j]
// Grid (32 mt, 16 tb), 256 thr.
// ---------------------------------------------------------------------------
__global__ __launch_bounds__(256)
void xconv_kernel(const float* __restrict__ x, _Float16* __restrict__ xf)
{
    __shared__ float xs[16][2][128];
    const int mt = blockIdx.x, tb = blockIdx.y;
    const int t = threadIdx.x;
    for (int tl = 0; tl < 8; ++tl) {
        __syncthreads();
#pragma unroll
        for (int i = 0; i < 4; ++i) {
            const int idx = t + i * 256;
            const int m = idx >> 6, rest = idx & 63;
            const int t2 = rest >> 5, k4 = rest & 31;
            float4v v = *(const float4v*)(x +
                ((size_t)(mt * 16 + m) * T_STEPS + (tb * 16 + tl * 2 + t2)) * NIN + k4 * 4);
            *(float4v*)&xs[m][t2][k4 * 4] = v;
        }
        __syncthreads();
#pragma unroll
        for (int i = 0; i < 2; ++i) {
            const int idx = t + i * 256;
            const int t2 = idx >> 8, rest = idx & 255;
            const int kt = rest >> 6, lane = rest & 63;
            half8 hv;
#pragma unroll
            for (int j = 0; j < 8; ++j)
                hv[j] = (_Float16)xs[lane & 15][t2][kt * 32 + (lane >> 4) * 8 + j];
            const int tg = tb * 16 + tl * 2 + t2;
            *(half8*)(xf + (((size_t)tg * 32 + mt) * 4 + kt) * 512 + lane * 8) = hv;
        }
    }
}

// ---------------------------------------------------------------------------
// Persistent kernel.  256 WGs x 512 thr, 1 WG/CU (152 KB LDS).
// XCD-SEGREGATED mapping (bid%8 -> XCD on gfx950):
//   xcd = bid&7; layer = xcd>>2 (XCDs 0-3 = layer 0, XCDs 4-7 = layer 1);
//   s = (xcd&3)*32 + (bid>>3).
// Each XCD's L2 then holds exactly ONE 2MB A-buffer per phase -> the 64 MB/XCD
// A-broadcast fan-out is served at L2 BW instead of thrashing to LLC.
// Per-WG K-loop stagger (koff) avoids lockstep same-line streaming.
// GEMM: M=512 (8 waves x 4 mt), N=32 (2 nt), K=2048 (64 kt).
// ---------------------------------------------------------------------------
__global__ __launch_bounds__(512, 2)
void persist_kernel(const float* __restrict__ k1, const float* __restrict__ b1,
                    const float* __restrict__ k2, const float* __restrict__ b2,
                    const float* __restrict__ W_h, const float* __restrict__ b_h,
                    const _Float16* __restrict__ xf,
                    uint8_t* wsb, float* __restrict__ out,
                    uint32_t* barrier_mem)
{
    extern __shared__ __align__(16) char smem[];
    const size_t MB = 1024 * 1024;
    _Float16* A1b[2] = {(_Float16*)(wsb + 0 * MB), (_Float16*)(wsb + 2 * MB)};
    _Float16* A2b[2] = {(_Float16*)(wsb + 4 * MB), (_Float16*)(wsb + 6 * MB)};
    uint32_t* cnt = barrier_mem;
    uint32_t* gen = barrier_mem + 32;

    const int tid = threadIdx.x;
    const int w = tid >> 6, lane = tid & 63;
    const int q = lane >> 4, n16 = lane & 15;
    const int bid = blockIdx.x;
    const int xcd = bid & 7;
    const int layer = xcd >> 2;              // XCDs 0-3: layer 0; 4-7: layer 1
    const int s = (xcd & 3) * 32 + (bid >> 3);   // 0..127, bijective per layer
    const int u0 = s * 8;
    const int koff = (s & 31) * 2;           // per-WG K-loop stagger within XCD

    const float* ksrc = layer ? k2 : k1;
    const float* bsrc = layer ? b2 : b1;

    // ---- init: convert weight slice f32 -> fp16 frags in LDS ----
    {
#pragma unroll 1
        for (int i = 0; i < 16; ++i) {
            const int kt = w * 8 + (i & 7);
            const int nt = i >> 3;
            const int colg = (nt * 2 + (n16 >> 3)) * 1024 + u0 + (n16 & 7);
            half8 hv;
#pragma unroll
            for (int j = 0; j < 8; ++j)
                hv[j] = (_Float16)ksrc[(size_t)(kt * 32 + q * 8 + j) * 4096 + colg];
            *(half8*)(smem + WLDS_OFF + (nt * 64 + kt) * 1024 + lane * 16) = hv;
        }
    }
    if (tid < 32)
        ((float*)(smem + BIASG_OFF))[tid] = bsrc[(tid >> 3) * 1024 + u0 + (tid & 7)];
    if (layer == 1) {   // proj lives on layer-1 WGs
        if (tid < 256) {
            const int kt = tid >> 6, ln = tid & 63;
            const int nn = ln & 15;
            half8 hv;
#pragma unroll
            for (int j = 0; j < 8; ++j) {
                float v = (nn < 8)
                    ? W_h[(size_t)(kt * 32 + (ln >> 4) * 8 + j) * NHID + u0 + nn] : 0.f;
                hv[j] = (_Float16)v;
            }
            *(half8*)(smem + WHF_OFF + kt * 1024 + ln * 16) = hv;
        }
        if (tid < 8) ((float*)(smem + BH_OFF))[tid] = b_h[u0 + tid];
    }
    __syncthreads();

    const float* bg = (const float*)(smem + BIASG_OFF);
    const float* bh = (const float*)(smem + BH_OFF);
    float* zw = (float*)(smem + ZS_OFF + w * ZW_BYTES);     // [16 rows][36 f32]
    _Float16* hw = (_Float16*)(smem + HS_OFF + w * 256);    // [16 rows][8 u]

    // c state: lane owns (row = n16, units q*2, q*2+1) per mt
    float cst[4][2];
#pragma unroll
    for (int mt = 0; mt < 4; ++mt) { cst[mt][0] = 0.f; cst[mt][1] = 0.f; }

    // ---- proj body (layer-1 WGs): pf(t) -> A1dst low half ----
    auto proj_step = [&](int tstep, _Float16* A1dst) {
        float4v pacc[4];
#pragma unroll
        for (int mt = 0; mt < 4; ++mt) pacc[mt] = (float4v){0.f, 0.f, 0.f, 0.f};
        half8 Bp[4];
        half8 Ap[4][4];
#pragma unroll
        for (int kt = 0; kt < 4; ++kt) {
            Bp[kt] = *(const half8*)(smem + WHF_OFF + kt * 1024 + lane * 16);
#pragma unroll
            for (int mt = 0; mt < 4; ++mt)
                Ap[kt][mt] = *(const half8*)(xf +
                    (((size_t)tstep * 32 + (w * 4 + mt)) * 4 + kt) * 512 + lane * 8);
        }
#pragma unroll
        for (int kt = 0; kt < 4; ++kt)
#pragma unroll
            for (int mt = 0; mt < 4; ++mt)
                pacc[mt] = __builtin_amdgcn_mfma_f32_16x16x32_f16(Ap[kt][mt], Bp[kt], pacc[mt], 0, 0, 0);
#pragma unroll 1
        for (int mt = 0; mt < 4; ++mt) {
            if (n16 < 8) {
#pragma unroll
                for (int r = 0; r < 4; ++r)
                    zw[(q * 4 + r) * 9 + n16] = pacc[mt][r];   // stride 9: conflict-free
            }
            if (lane < 16) {        // wave-internal LDS: DS ops in-order per wave
                half8 hv;
#pragma unroll
                for (int u = 0; u < 8; ++u)
                    hv[u] = (_Float16)fmaxf(zw[lane * 9 + u] + bh[u], 0.f);
                const int mtg = w * 4 + mt;
                *(half8*)(A1dst + ((size_t)mtg * 64 + (s >> 2)) * 512
                                + ((s & 3) * 16 + lane) * 8) = hv;
            }
        }
    };

    // ---- LSTM GEMM + fused epilogue, staggered K loop ----
    auto gemm_step = [&](const _Float16* Asrc, _Float16* hdst1, _Float16* hdst2,
                         float* outp) {
        float4v acc[4][2];
#pragma unroll
        for (int mt = 0; mt < 4; ++mt) {
            acc[mt][0] = (float4v){0.f, 0.f, 0.f, 0.f};
            acc[mt][1] = (float4v){0.f, 0.f, 0.f, 0.f};
        }
        const char* aw[4];
#pragma unroll
        for (int mt = 0; mt < 4; ++mt)
            aw[mt] = (const char*)Asrc + ((size_t)(w * 4 + mt) * 64) * 1024 + lane * 16;
        auto kaddr = [&](int k) -> int { return (k + koff) & 63; };

        half8 Ab[4][4];
#pragma unroll
        for (int d = 0; d < 3; ++d)
#pragma unroll
            for (int mt = 0; mt < 4; ++mt)
                Ab[d][mt] = *(const half8*)(aw[mt] + (size_t)kaddr(d) * 1024);
        half8 Bb[2][2];
        Bb[0][0] = *(const half8*)(smem + WLDS_OFF + kaddr(0) * 1024 + lane * 16);
        Bb[0][1] = *(const half8*)(smem + WLDS_OFF + 65536 + kaddr(0) * 1024 + lane * 16);

#pragma unroll 4
        for (int kt = 0; kt < 60; ++kt) {
            const int cur = kt & 3, nxt = (kt + 3) & 3, bc = kt & 1;
#pragma unroll
            for (int mt = 0; mt < 4; ++mt)
                Ab[nxt][mt] = *(const half8*)(aw[mt] + (size_t)kaddr(kt + 3) * 1024);
            Bb[bc ^ 1][0] = *(const half8*)(smem + WLDS_OFF + kaddr(kt + 1) * 1024 + lane * 16);
            Bb[bc ^ 1][1] = *(const half8*)(smem + WLDS_OFF + 65536 + kaddr(kt + 1) * 1024 + lane * 16);
#pragma unroll
            for (int mt = 0; mt < 4; ++mt)
                acc[mt][0] = __builtin_amdgcn_mfma_f32_16x16x32_f16(Ab[cur][mt], Bb[bc][0], acc[mt][0], 0, 0, 0);
#pragma unroll
            for (int mt = 0; mt < 4; ++mt)
                acc[mt][1] = __builtin_amdgcn_mfma_f32_16x16x32_f16(Ab[cur][mt], Bb[bc][1], acc[mt][1], 0, 0, 0);
        }
#pragma unroll
        for (int kt = 60; kt < 64; ++kt) {
            const int cur = kt & 3, bc = kt & 1;
            if (kt == 60) {
#pragma unroll
                for (int mt = 0; mt < 4; ++mt)
                    Ab[3][mt] = *(const half8*)(aw[mt] + (size_t)kaddr(63) * 1024);
            }
            if (kt < 63) {
                Bb[bc ^ 1][0] = *(const half8*)(smem + WLDS_OFF + kaddr(kt + 1) * 1024 + lane * 16);
                Bb[bc ^ 1][1] = *(const half8*)(smem + WLDS_OFF + 65536 + kaddr(kt + 1) * 1024 + lane * 16);
            }
#pragma unroll
            for (int mt = 0; mt < 4; ++mt)
                acc[mt][0] = __builtin_amdgcn_mfma_f32_16x16x32_f16(Ab[cur][mt], Bb[bc][0], acc[mt][0], 0, 0, 0);
#pragma unroll
            for (int mt = 0; mt < 4; ++mt)
                acc[mt][1] = __builtin_amdgcn_mfma_f32_16x16x32_f16(Ab[cur][mt], Bb[bc][1], acc[mt][1], 0, 0, 0);
        }

        // epilogue per mt (cols: g*8+u), zw stride 36
#pragma unroll 1
        for (int mt = 0; mt < 4; ++mt) {
#pragma unroll
            for (int nt = 0; nt < 2; ++nt)
#pragma unroll
                for (int r = 0; r < 4; ++r)
                    zw[(q * 4 + r) * 36 + nt * 16 + n16] = acc[mt][nt][r];
            const float* zr = zw + n16 * 36 + q * 2;
            float2v vi = *(const float2v*)(zr + 0);
            float2v vj = *(const float2v*)(zr + 8);
            float2v vf = *(const float2v*)(zr + 16);
            float2v vo = *(const float2v*)(zr + 24);
            float hvals[2];
#pragma unroll
            for (int uu = 0; uu < 2; ++uu) {
                const int u = q * 2 + uu;
                const float zi = vi[uu] + bg[u];
                const float zj = vj[uu] + bg[8 + u];
                const float zf = vf[uu] + bg[16 + u];
                const float zo = vo[uu] + bg[24 + u];
                float c = cst[mt][uu] * sigmoid_f(zf + 1.0f) + sigmoid_f(zi) * tanh_f(zj);
                cst[mt][uu] = c;
                hvals[uu] = tanh_f(c) * sigmoid_f(zo);
            }
            hw[n16 * 8 + q * 2 + 0] = (_Float16)hvals[0];
            hw[n16 * 8 + q * 2 + 1] = (_Float16)hvals[1];
            if (outp) {
                const int row = (w * 4 + mt) * 16 + n16;
                outp[(size_t)row * NHID + u0 + q * 2 + 0] = hvals[0];
                outp[(size_t)row * NHID + u0 + q * 2 + 1] = hvals[1];
            }
            if (lane < 16) {
                half8 hv = *(half8*)(hw + lane * 8);
                const size_t loff = ((s & 3) * 16 + lane) * 8;
                const int mtg = w * 4 + mt;
                *(half8*)(hdst1 + ((size_t)mtg * 64 + 32 + (s >> 2)) * 512 + loff) = hv;
                if (hdst2)
                    *(half8*)(hdst2 + ((size_t)mtg * 64 + (s >> 2)) * 512 + loff) = hv;
            }
        }
    };

    // ---- pre-phase: proj(0) -> A1[0].low (layer-1 WGs) ----
    if (layer == 1) proj_step(0, A1b[0]);
    grid_barrier(cnt, gen, 1u);

    // ---- phases ----
    for (int p = 0; p <= 256; ++p) {
        const int pi = p & 1, po = pi ^ 1;
        if (layer == 0) {
            if (p <= 255)
                gemm_step(A1b[pi], A1b[po], A2b[po], nullptr);   // h1 -> A1hi, A2lo
        } else {
            if (p >= 1)
                gemm_step(A2b[pi], A2b[po], nullptr,
                          (p == 256) ? out : nullptr);           // h2 -> A2hi
            if (p + 1 <= 255)
                proj_step(p + 1, A1b[po]);                       // pf(t+1) -> A1lo
        }
        grid_barrier(cnt, gen, (uint32_t)(p + 2));
    }
}

// ---------------------------------------------------------------------------
extern "C" void kernel_launch(void* const* d_in, const int* in_sizes, int n_in,
                              void* d_out, int out_size, void* d_ws, size_t ws_size,
                              hipStream_t stream)
{
    const float* x   = (const float*)d_in[0];
    const float* W_h = (const float*)d_in[1];
    const float* b_h = (const float*)d_in[2];
    const float* k1  = (const float*)d_in[3];
    const float* b1  = (const float*)d_in[4];
    const float* k2  = (const float*)d_in[5];
    const float* b2  = (const float*)d_in[6];
    float* out = (float*)d_out;

    const size_t MB = 1024 * 1024;
    uint8_t* wsb = (uint8_t*)d_ws;
    // A1[0] 0-2, A1[1] 2-4, A2[0] 4-6, A2[1] 6-8 MB ; xf 8-40 MB ; barrier @40 MB
    _Float16* xf = (_Float16*)(wsb + 8 * MB);
    uint32_t* barrier_mem = (uint32_t*)(wsb + 40 * MB);

    hipFuncSetAttribute((const void*)persist_kernel,
                        hipFuncAttributeMaxDynamicSharedMemorySize, SMEM_BYTES);

    hipMemsetAsync(wsb, 0, 8 * MB, stream);          // zero all A-buffers
    hipMemsetAsync(barrier_mem, 0, 4096, stream);
    xconv_kernel<<<dim3(32, 16), 256, 0, stream>>>(x, xf);
    persist_kernel<<<NWGS, 512, SMEM_BYTES, stream>>>(
        k1, b1, k2, b2, W_h, b_h, xf, wsb, out, barrier_mem);
}

// Round 4
// 9294.520 us; speedup vs baseline: 1.1024x; 1.0595x over previous
//
#include <hip/hip_runtime.h>
#include <cstddef>
#include <cstdint>

#define T_STEPS 256
#define BATCH   512
#define NIN     128
#define NHID    1024
#define NWGS    256

typedef _Float16 half8  __attribute__((ext_vector_type(8)));
typedef float    float4v __attribute__((ext_vector_type(4)));
typedef float    float2v __attribute__((ext_vector_type(2)));

__device__ __forceinline__ float sigmoid_f(float x) { return 1.0f / (1.0f + __expf(-x)); }
__device__ __forceinline__ float tanh_f(float x) {
    float ax = fabsf(x);
    float t  = __expf(-2.0f * ax);
    float r  = (1.0f - t) / (1.0f + t);
    return copysignf(r, x);
}

// LDS map (dynamic, ~152 KB)
#define WLDS_OFF  0         // 131072 B: weight B-frags [nt 2][kt 64][lane 64][16B]
#define WHF_OFF   131072    // 4096 B:  proj B-frags [kt 4][lane 64][16B]
#define ZS_OFF    135168    // 18432 B: per-wave z scratch (2304 B each, 16 rows x 36 f32)
#define ZW_BYTES  2304
#define HS_OFF    153600    // 2048 B:  per-wave h scratch (256 B each)
#define BIASG_OFF 155648    // 128 B:   gate bias [g 4][u 8] f32
#define BH_OFF    155776    // 32 B:    proj bias [u 8] f32
#define SMEM_BYTES 155808

// ---------------------------------------------------------------------------
// Tree grid barrier: 8 sub-counters (per bid&7 group of 32 WGs, 128 B apart)
// fan into a master counter -> gen. Monotonic counters, never reset.
// Layout (uint32 idx): sub[g] at g*32, master at 256, gen at 320.
// ---------------------------------------------------------------------------
__device__ __forceinline__ void grid_barrier(uint32_t* bm, uint32_t target_gen,
                                             int grp) {
    __syncthreads();
    if (threadIdx.x == 0) {
        __threadfence();
        uint32_t old = __hip_atomic_fetch_add(bm + grp * 32, 1u, __ATOMIC_RELAXED,
                                              __HIP_MEMORY_SCOPE_AGENT);
        if (old == target_gen * 32u - 1u) {
            uint32_t mold = __hip_atomic_fetch_add(bm + 256, 1u, __ATOMIC_RELAXED,
                                                   __HIP_MEMORY_SCOPE_AGENT);
            if (mold == target_gen * 8u - 1u)
                __hip_atomic_store(bm + 320, target_gen, __ATOMIC_RELAXED,
                                   __HIP_MEMORY_SCOPE_AGENT);
        }
        uint32_t spins = 0;
        while (__hip_atomic_load(bm + 320, __ATOMIC_RELAXED,
                                 __HIP_MEMORY_SCOPE_AGENT) < target_gen) {
            __builtin_amdgcn_s_sleep(8);
            if (++spins > 20000000u) break;
        }
        __threadfence();
    }
    __syncthreads();
}

// ---------------------------------------------------------------------------
// One-time x -> fp16 A-frag conversion.
// xf[t 256][mt 32][kt 4][512 halves]; value = x[mt*16+(lane&15)][t][kt*32+(lane>>4)*8+j]
// Grid (32 mt, 16 tb), 256 thr.
// ---------------------------------------------------------------------------
__global__ __launch_bounds__(256)
void xconv_kernel(const float* __restrict__ x, _Float16* __restrict__ xf)
{
    __shared__ float xs[16][2][128];
    const int mt = blockIdx.x, tb = blockIdx.y;
    const int t = threadIdx.x;
    for (int tl = 0; tl < 8; ++tl) {
        __syncthreads();
#pragma unroll
        for (int i = 0; i < 4; ++i) {
            const int idx = t + i * 256;
            const int m = idx >> 6, rest = idx & 63;
            const int t2 = rest >> 5, k4 = rest & 31;
            float4v v = *(const float4v*)(x +
                ((size_t)(mt * 16 + m) * T_STEPS + (tb * 16 + tl * 2 + t2)) * NIN + k4 * 4);
            *(float4v*)&xs[m][t2][k4 * 4] = v;
        }
        __syncthreads();
#pragma unroll
        for (int i = 0; i < 2; ++i) {
            const int idx = t + i * 256;
            const int t2 = idx >> 8, rest = idx & 255;
            const int kt = rest >> 6, lane = rest & 63;
            half8 hv;
#pragma unroll
            for (int j = 0; j < 8; ++j)
                hv[j] = (_Float16)xs[lane & 15][t2][kt * 32 + (lane >> 4) * 8 + j];
            const int tg = tb * 16 + tl * 2 + t2;
            *(half8*)(xf + (((size_t)tg * 32 + mt) * 4 + kt) * 512 + lane * 8) = hv;
        }
    }
}

// ---------------------------------------------------------------------------
// Persistent kernel.  256 WGs x 512 thr, 1 WG/CU (152 KB LDS).
// xcd = bid&7; layer = xcd>>2; s = (xcd&3)*32 + (bid>>3).
// GEMM K-loop: counted-vmcnt register pipeline, PRESSURE-SAFE version:
//   2-kt load groups (8 x global_load_dwordx4 = 32 VGPR), depth 3 (96 VGPR
//   in flight). Waits tie the group's regs as "+v" so MFMAs depend on the
//   post-wait values; sched_barrier(0) fences scheduling (rule #18).
//   Steady state: 24 loads outstanding, vmcnt(16) per slot.
// ---------------------------------------------------------------------------
__global__ __launch_bounds__(512, 2)
void persist_kernel(const float* __restrict__ k1, const float* __restrict__ b1,
                    const float* __restrict__ k2, const float* __restrict__ b2,
                    const float* __restrict__ W_h, const float* __restrict__ b_h,
                    const _Float16* __restrict__ xf,
                    uint8_t* wsb, float* __restrict__ out,
                    uint32_t* barrier_mem)
{
    extern __shared__ __align__(16) char smem[];
    const size_t MB = 1024 * 1024;
    _Float16* A1b[2] = {(_Float16*)(wsb + 0 * MB), (_Float16*)(wsb + 2 * MB)};
    _Float16* A2b[2] = {(_Float16*)(wsb + 4 * MB), (_Float16*)(wsb + 6 * MB)};

    const int tid = threadIdx.x;
    const int w = tid >> 6, lane = tid & 63;
    const int q = lane >> 4, n16 = lane & 15;
    const int bid = blockIdx.x;
    const int xcd = bid & 7;
    const int layer = xcd >> 2;              // XCDs 0-3: layer 0; 4-7: layer 1
    const int s = (xcd & 3) * 32 + (bid >> 3);   // 0..127, bijective per layer
    const int u0 = s * 8;

    const float* ksrc = layer ? k2 : k1;
    const float* bsrc = layer ? b2 : b1;

    // ---- init: convert weight slice f32 -> fp16 frags in LDS ----
    {
#pragma unroll 1
        for (int i = 0; i < 16; ++i) {
            const int kt = w * 8 + (i & 7);
            const int nt = i >> 3;
            const int colg = (nt * 2 + (n16 >> 3)) * 1024 + u0 + (n16 & 7);
            half8 hv;
#pragma unroll
            for (int j = 0; j < 8; ++j)
                hv[j] = (_Float16)ksrc[(size_t)(kt * 32 + q * 8 + j) * 4096 + colg];
            *(half8*)(smem + WLDS_OFF + (nt * 64 + kt) * 1024 + lane * 16) = hv;
        }
    }
    if (tid < 32)
        ((float*)(smem + BIASG_OFF))[tid] = bsrc[(tid >> 3) * 1024 + u0 + (tid & 7)];
    if (layer == 1) {   // proj lives on layer-1 WGs
        if (tid < 256) {
            const int kt = tid >> 6, ln = tid & 63;
            const int nn = ln & 15;
            half8 hv;
#pragma unroll
            for (int j = 0; j < 8; ++j) {
                float v = (nn < 8)
                    ? W_h[(size_t)(kt * 32 + (ln >> 4) * 8 + j) * NHID + u0 + nn] : 0.f;
                hv[j] = (_Float16)v;
            }
            *(half8*)(smem + WHF_OFF + kt * 1024 + ln * 16) = hv;
        }
        if (tid < 8) ((float*)(smem + BH_OFF))[tid] = b_h[u0 + tid];
    }
    __syncthreads();

    const float* bg = (const float*)(smem + BIASG_OFF);
    const float* bh = (const float*)(smem + BH_OFF);
    float* zw = (float*)(smem + ZS_OFF + w * ZW_BYTES);     // [16 rows][36 f32]
    _Float16* hw = (_Float16*)(smem + HS_OFF + w * 256);    // [16 rows][8 u]

    // c state: lane owns (row = n16, units q*2, q*2+1) per mt
    float cst[4][2];
#pragma unroll
    for (int mt = 0; mt < 4; ++mt) { cst[mt][0] = 0.f; cst[mt][1] = 0.f; }

    // ---- proj body (layer-1 WGs): pf(t) -> A1dst low half ----
    auto proj_step = [&](int tstep, _Float16* A1dst) {
        float4v pacc[4];
#pragma unroll
        for (int mt = 0; mt < 4; ++mt) pacc[mt] = (float4v){0.f, 0.f, 0.f, 0.f};
        half8 Bp[4];
        half8 Ap[4][4];
#pragma unroll
        for (int kt = 0; kt < 4; ++kt) {
            Bp[kt] = *(const half8*)(smem + WHF_OFF + kt * 1024 + lane * 16);
#pragma unroll
            for (int mt = 0; mt < 4; ++mt)
                Ap[kt][mt] = *(const half8*)(xf +
                    (((size_t)tstep * 32 + (w * 4 + mt)) * 4 + kt) * 512 + lane * 8);
        }
#pragma unroll
        for (int kt = 0; kt < 4; ++kt)
#pragma unroll
            for (int mt = 0; mt < 4; ++mt)
                pacc[mt] = __builtin_amdgcn_mfma_f32_16x16x32_f16(Ap[kt][mt], Bp[kt], pacc[mt], 0, 0, 0);
#pragma unroll 1
        for (int mt = 0; mt < 4; ++mt) {
            if (n16 < 8) {
#pragma unroll
                for (int r = 0; r < 4; ++r)
                    zw[(q * 4 + r) * 9 + n16] = pacc[mt][r];   // stride 9: conflict-free
            }
            if (lane < 16) {        // wave-internal LDS: DS ops in-order per wave
                half8 hv;
#pragma unroll
                for (int u = 0; u < 8; ++u)
                    hv[u] = (_Float16)fmaxf(zw[lane * 9 + u] + bh[u], 0.f);
                const int mtg = w * 4 + mt;
                *(half8*)(A1dst + ((size_t)mtg * 64 + (s >> 2)) * 512
                                + ((s & 3) * 16 + lane) * 8) = hv;
            }
        }
    };

    // ---- LSTM GEMM + fused epilogue; depth-3 counted-vmcnt asm pipeline ----
    auto gemm_step = [&](const _Float16* Asrc, _Float16* hdst1, _Float16* hdst2,
                         float* outp) {
        float4v acc[4][2];
#pragma unroll
        for (int mt = 0; mt < 4; ++mt) {
            acc[mt][0] = (float4v){0.f, 0.f, 0.f, 0.f};
            acc[mt][1] = (float4v){0.f, 0.f, 0.f, 0.f};
        }
        const char* aw[4];
#pragma unroll
        for (int mt = 0; mt < 4; ++mt)
            aw[mt] = (const char*)Asrc + ((size_t)(w * 4 + mt) * 64) * 1024 + lane * 16;

        half8 G0[8], G1[8], G2[8];   // 3 groups x 2 kt x 4 mt, static indexing

        // issue 8 asm loads for kts [kb, kb+2) into buf
#define ISSUE2(buf, kb)                                                         \
        do {                                                                    \
            _Pragma("unroll")                                                   \
            for (int kk = 0; kk < 2; ++kk) {                                    \
                _Pragma("unroll")                                               \
                for (int mt = 0; mt < 4; ++mt)                                  \
                    asm volatile("global_load_dwordx4 %0, %1, off"              \
                                 : "=&v"(buf[kk * 4 + mt])                      \
                                 : "v"(aw[mt] + (size_t)((kb) + kk) * 1024));   \
            }                                                                   \
        } while (0)

        // wait until <=n VMEM outstanding; ties buf regs so MFMAs see
        // post-wait values (cannot be hoisted past the wait)
#define WAITG(n, buf)                                                           \
        do {                                                                    \
            asm volatile("s_waitcnt vmcnt(" #n ")"                              \
                : "+v"(buf[0]), "+v"(buf[1]), "+v"(buf[2]), "+v"(buf[3]),       \
                  "+v"(buf[4]), "+v"(buf[5]), "+v"(buf[6]), "+v"(buf[7]));      \
            __builtin_amdgcn_sched_barrier(0);                                  \
        } while (0)

        // 2 kts of MFMA from buf (B frags from LDS, compiler-scheduled)
#define MFMA2(buf, kb)                                                          \
        do {                                                                    \
            _Pragma("unroll")                                                   \
            for (int kk = 0; kk < 2; ++kk) {                                    \
                half8 B0 = *(const half8*)(smem + WLDS_OFF                      \
                              + (size_t)((kb) + kk) * 1024 + lane * 16);        \
                half8 B1 = *(const half8*)(smem + WLDS_OFF + 65536              \
                              + (size_t)((kb) + kk) * 1024 + lane * 16);        \
                _Pragma("unroll")                                               \
                for (int mt = 0; mt < 4; ++mt)                                  \
                    acc[mt][0] = __builtin_amdgcn_mfma_f32_16x16x32_f16(        \
                        buf[kk * 4 + mt], B0, acc[mt][0], 0, 0, 0);             \
                _Pragma("unroll")                                               \
                for (int mt = 0; mt < 4; ++mt)                                  \
                    acc[mt][1] = __builtin_amdgcn_mfma_f32_16x16x32_f16(        \
                        buf[kk * 4 + mt], B1, acc[mt][1], 0, 0, 0);             \
            }                                                                   \
        } while (0)

        ISSUE2(G0, 0);
        ISSUE2(G1, 2);
        ISSUE2(G2, 4);               // 24 outstanding
#pragma unroll 1
        for (int g3 = 0; g3 < 10; ++g3) {
            const int kb = g3 * 6;
            WAITG(16, G0);           // oldest group (G0) complete
            MFMA2(G0, kb);
            ISSUE2(G0, kb + 6);      // g3=9 -> kt 60 (valid)
            WAITG(16, G1);
            MFMA2(G1, kb + 2);
            ISSUE2(G1, kb + 8);      // g3=9 -> kt 62 (valid)
            WAITG(16, G2);
            MFMA2(G2, kb + 4);
            if (g3 < 9)
                ISSUE2(G2, kb + 10);
        }
        // tail: G0 holds kt 60, G1 holds kt 62; 16 outstanding
        WAITG(8, G0);
        MFMA2(G0, 60);
        WAITG(0, G1);
        MFMA2(G1, 62);
#undef ISSUE2
#undef WAITG
#undef MFMA2

        // epilogue per mt (cols: g*8+u), zw stride 36
#pragma unroll 1
        for (int mt = 0; mt < 4; ++mt) {
#pragma unroll
            for (int nt = 0; nt < 2; ++nt)
#pragma unroll
                for (int r = 0; r < 4; ++r)
                    zw[(q * 4 + r) * 36 + nt * 16 + n16] = acc[mt][nt][r];
            const float* zr = zw + n16 * 36 + q * 2;
            float2v vi = *(const float2v*)(zr + 0);
            float2v vj = *(const float2v*)(zr + 8);
            float2v vf = *(const float2v*)(zr + 16);
            float2v vo = *(const float2v*)(zr + 24);
            float hvals[2];
#pragma unroll
            for (int uu = 0; uu < 2; ++uu) {
                const int u = q * 2 + uu;
                const float zi = vi[uu] + bg[u];
                const float zj = vj[uu] + bg[8 + u];
                const float zf = vf[uu] + bg[16 + u];
                const float zo = vo[uu] + bg[24 + u];
                float c = cst[mt][uu] * sigmoid_f(zf + 1.0f) + sigmoid_f(zi) * tanh_f(zj);
                cst[mt][uu] = c;
                hvals[uu] = tanh_f(c) * sigmoid_f(zo);
            }
            hw[n16 * 8 + q * 2 + 0] = (_Float16)hvals[0];
            hw[n16 * 8 + q * 2 + 1] = (_Float16)hvals[1];
            if (outp) {
                const int row = (w * 4 + mt) * 16 + n16;
                outp[(size_t)row * NHID + u0 + q * 2 + 0] = hvals[0];
                outp[(size_t)row * NHID + u0 + q * 2 + 1] = hvals[1];
            }
            if (lane < 16) {
                half8 hv = *(half8*)(hw + lane * 8);
                const size_t loff = ((s & 3) * 16 + lane) * 8;
                const int mtg = w * 4 + mt;
                *(half8*)(hdst1 + ((size_t)mtg * 64 + 32 + (s >> 2)) * 512 + loff) = hv;
                if (hdst2)
                    *(half8*)(hdst2 + ((size_t)mtg * 64 + (s >> 2)) * 512 + loff) = hv;
            }
        }
    };

    // ---- pre-phase: proj(0) -> A1[0].low (layer-1 WGs) ----
    if (layer == 1) proj_step(0, A1b[0]);
    grid_barrier(barrier_mem, 1u, xcd);

    // ---- phases ----
    for (int p = 0; p <= 256; ++p) {
        const int pi = p & 1, po = pi ^ 1;
        if (layer == 0) {
            if (p <= 255)
                gemm_step(A1b[pi], A1b[po], A2b[po], nullptr);   // h1 -> A1hi, A2lo
        } else {
            if (p >= 1)
                gemm_step(A2b[pi], A2b[po], nullptr,
                          (p == 256) ? out : nullptr);           // h2 -> A2hi
            if (p + 1 <= 255)
                proj_step(p + 1, A1b[po]);                       // pf(t+1) -> A1lo
        }
        grid_barrier(barrier_mem, (uint32_t)(p + 2), xcd);
    }
}

// ---------------------------------------------------------------------------
extern "C" void kernel_launch(void* const* d_in, const int* in_sizes, int n_in,
                              void* d_out, int out_size, void* d_ws, size_t ws_size,
                              hipStream_t stream)
{
    const float* x   = (const float*)d_in[0];
    const float* W_h = (const float*)d_in[1];
    const float* b_h = (const float*)d_in[2];
    const float* k1  = (const float*)d_in[3];
    const float* b1  = (const float*)d_in[4];
    const float* k2  = (const float*)d_in[5];
    const float* b2  = (const float*)d_in[6];
    float* out = (float*)d_out;

    const size_t MB = 1024 * 1024;
    uint8_t* wsb = (uint8_t*)d_ws;
    // A1[0] 0-2, A1[1] 2-4, A2[0] 4-6, A2[1] 6-8 MB ; xf 8-40 MB ; barrier @40 MB
    _Float16* xf = (_Float16*)(wsb + 8 * MB);
    uint32_t* barrier_mem = (uint32_t*)(wsb + 40 * MB);

    hipFuncSetAttribute((const void*)persist_kernel,
                        hipFuncAttributeMaxDynamicSharedMemorySize, SMEM_BYTES);

    hipMemsetAsync(wsb, 0, 8 * MB, stream);          // zero all A-buffers
    hipMemsetAsync(barrier_mem, 0, 4096, stream);
    xconv_kernel<<<dim3(32, 16), 256, 0, stream>>>(x, xf);
    persist_kernel<<<NWGS, 512, SMEM_BYTES, stream>>>(
        k1, b1, k2, b2, W_h, b_h, xf, wsb, out, barrier_mem);
}